// Round 14
// baseline (132.992 us; speedup 1.0000x reference)
//
#include <hip/hip_runtime.h>

// Problem constants
#define NBANDS 8
#define BS 32
#define MTF 41
#define IMG 552
#define CONV 512
#define QOUT 481
#define NIMG 32
#define NN 1024.0f
#define KXP 42            // Atab kx entries per band (41 real + 1 zero pad)

// Transposed fp16 input T: [NIMG][TX][TY], zero-padded
#define TX 560
#define TY 576

typedef _Float16 half8 __attribute__((ext_vector_type(8)));
typedef _Float16 half2v __attribute__((ext_vector_type(2)));
typedef float f32x16 __attribute__((ext_vector_type(16)));

// ---------- prep 1: transpose + fp16 convert ----------
__global__ __launch_bounds__(256) void prep_transpose(
    const float* __restrict__ in, _Float16* __restrict__ T)
{
    __shared__ _Float16 s[64][72];
    int bid = blockIdx.x;
    int img = bid / 81;            // 9x9 tiles of 64
    int t = bid % 81;
    int ty = t / 9, tx2 = t % 9;
    int y0 = ty * 64, x0 = tx2 * 64;
    const float* ip = in + (size_t)img * IMG * IMG;

    for (int k = 0; k < 16; ++k) {
        int i = k * 256 + threadIdx.x;
        int r = i >> 6, c = i & 63;
        int y = y0 + r, x = x0 + c;
        float v = (y < IMG && x < IMG) ? ip[(size_t)y * IMG + x] : 0.f;
        s[c][r] = (_Float16)v;
    }
    __syncthreads();
    _Float16* Tp = T + (size_t)img * TX * TY;
    for (int k = 0; k < 2; ++k) {
        int i = k * 256 + threadIdx.x;  // 512 = 64 xi * 8 g
        int xi = i >> 3, g = i & 7;
        int x = x0 + xi;
        if (x < TX) {
            half8 v = *(const half8*)&s[xi][g * 8];
            *(half8*)&Tp[(size_t)x * TY + y0 + g * 8] = v;
        }
    }
}

// ---------- prep 2: Toeplitz A-table for 32x32x16 MFMA (42 kx, last = zeros) ----------
__global__ __launch_bounds__(320) void prep_atab32(
    const float* __restrict__ w, _Float16* __restrict__ A)
{
    int bid = blockIdx.x;                 // band*KXP + kx
    int band = bid / KXP, kx = bid % KXP;
    int s = threadIdx.x >> 6, lane = threadIdx.x & 63;
    int i = lane & 31;
    int kb = 16 * s + ((lane >> 5) << 3);
    const float* wp = w + band * MTF * MTF;
    half8 v;
#pragma unroll
    for (int j = 0; j < 8; ++j) {
        int ky = kb + j - i;
        v[j] = (kx < MTF && ky >= 0 && ky < MTF) ? (_Float16)wp[ky * MTF + kx]
                                                 : (_Float16)0.f;
    }
    *(half8*)&A[(((size_t)bid * 5 + s) << 9) + lane * 8] = v;
}

// ---------- Kernel A: 32x32x16 MFMA conv, 512 thr, 128y x 256x, 1 block/CU ----------
// 8 waves, wave = 128y x 32x. LDS: 22 8-row y-groups x 296 x-cols = 104192 B.
#define XP4 296
#define GSTR4 (2 * XP4 * 16)   // byte stride between B[j] groups (9472)

__global__ __launch_bounds__(512, 2) void conv_mfma_512(
    const _Float16* __restrict__ T, const _Float16* __restrict__ Atab,
    float* __restrict__ out)
{
    extern __shared__ _Float16 sB[];   // 22*296*8 halfs = 104192 B
    int bid = blockIdx.x;
    int img = bid >> 3;
    int rr  = bid & 7;
    int yb  = rr >> 1, xb = rr & 1;
    int y0 = yb << 7;          // 0..384
    int x0 = xb << 8;          // 0 or 256
    int band = img & 7;
    int tid = threadIdx.x;

    const _Float16* Tp = T + (size_t)img * TX * TY;
    for (int e = tid; e < 22 * XP4; e += 512) {
        int g = e / XP4, x = e - g * XP4;
        half8 v = *(const half8*)&Tp[(size_t)(x0 + x) * TY + y0 + g * 8];
        *(half8*)&sB[(size_t)e * 8] = v;
    }
    __syncthreads();

    int l  = tid & 63;
    int wx = tid >> 6;          // 0..7 (x sub-tile)
    int p  = l >> 5;            // k-parity (8-row group offset)
    int ln = l & 31;

    const half8* Ab = (const half8*)(Atab + (((size_t)band * KXP * 5) << 9)) + l;
    const char* bbase = (const char*)sB + ((size_t)(p * XP4 + (wx << 5) + ln) << 4);

    // 4 accumulator chains, one per 32-row y-sub-tile
    f32x16 acc0 = {}, acc1 = {}, acc2 = {}, acc3 = {};

    auto LDA = [&](half8 (&A)[5], int kx) {
        const half8* q = Ab + (size_t)kx * 5 * 64;
#pragma unroll
        for (int s = 0; s < 5; ++s) A[s] = q[(size_t)s * 64];
    };
    auto LDB = [&](half8 (&B)[11], int kx) {
        const char* q = bbase + ((size_t)kx << 4);
#pragma unroll
        for (int j = 0; j < 11; ++j) B[j] = *(const half8*)(q + j * GSTR4);
    };
    auto FMAS = [&](half8 (&A)[5], half8 (&B)[11]) {
        // rotate chains: same-chain reuse gap = 4 MFMA issues
#pragma unroll
        for (int s = 0; s < 5; ++s) {
            acc0 = __builtin_amdgcn_mfma_f32_32x32x16_f16(A[s], B[s],     acc0, 0, 0, 0);
            acc1 = __builtin_amdgcn_mfma_f32_32x32x16_f16(A[s], B[s + 2], acc1, 0, 0, 0);
            acc2 = __builtin_amdgcn_mfma_f32_32x32x16_f16(A[s], B[s + 4], acc2, 0, 0, 0);
            acc3 = __builtin_amdgcn_mfma_f32_32x32x16_f16(A[s], B[s + 6], acc3, 0, 0, 0);
        }
    };

    half8 A0[5], A1[5], B0[11], B1[11];
    LDA(A0, 0);
    LDA(A1, 1);
    LDB(B0, 0);
#pragma unroll 1
    for (int kx = 0; kx < 40; kx += 2) {
        LDB(B1, kx + 1);                      // prefetch B(kx+1)
        FMAS(A0, B0);                         // compute on B(kx)
        LDA(A0, kx + 2);                      // <= 40
        LDB(B0, kx + 2);                      // prefetch B(kx+2)
        FMAS(A1, B1);
        LDA(A1, kx + 3);                      // <= 41 (zero-padded slab)
    }
    FMAS(A0, B0);                             // kx = 40

    // C/D layout (32x32): col = l&31, row = (r&3) + 8*(r>>2) + 4*(l>>5)
    float* op = out + (size_t)img * CONV * CONV;
    int colb = x0 + (wx << 5) + ln;
    int rb   = y0 + (p << 2);
#pragma unroll
    for (int r2 = 0; r2 < 16; ++r2) {
        int rowo = (r2 & 3) + ((r2 >> 2) << 3);
        op[(size_t)(rb + rowo) * CONV + colb]       = acc0[r2];
        op[(size_t)(rb + 32 + rowo) * CONV + colb]  = acc1[r2];
        op[(size_t)(rb + 64 + rowo) * CONV + colb]  = acc2[r2];
        op[(size_t)(rb + 96 + rowo) * CONV + colb]  = acc3[r2];
    }
}

// ---------------- Kernel B: box-sums + Q, 4 chains/wave, packed-f16 scans ----------------
template<int C, int RM, int BM, bool BC>
__device__ __forceinline__ int dppadd_h2(int v) {
    int t = __builtin_amdgcn_update_dpp(0, v, C, RM, BM, BC);
    half2v a = __builtin_bit_cast(half2v, v);
    half2v b = __builtin_bit_cast(half2v, t);
    return __builtin_bit_cast(int, a + b);
}

__device__ __forceinline__ int wave_iscan_h2(int v) {
    v = dppadd_h2<0x111, 0xf, 0xf, true >(v);   // row_shr:1
    v = dppadd_h2<0x112, 0xf, 0xf, true >(v);   // row_shr:2
    v = dppadd_h2<0x114, 0xf, 0xf, true >(v);   // row_shr:4
    v = dppadd_h2<0x118, 0xf, 0xf, true >(v);   // row_shr:8
    v = dppadd_h2<0x142, 0xa, 0xf, false>(v);   // row_bcast:15 -> rows 1,3
    v = dppadd_h2<0x143, 0xc, 0xf, false>(v);   // row_bcast:31 -> rows 2,3
    return v;
}

// packed window-sum over lanes [l, l+31] for two channels at once
__device__ __forceinline__ void win32pair(float sa, float sb, int lane,
                                          float& wa, float& wb) {
    half2v p = __builtin_bit_cast(half2v, __builtin_amdgcn_cvt_pkrtz(sa, sb));
    int P = wave_iscan_h2(__builtin_bit_cast(int, p));
    int Pg = __shfl(P, lane + 31, 64);
    half2v w = __builtin_bit_cast(half2v, Pg) - __builtin_bit_cast(half2v, P) + p;
    wa = (float)w[0];
    wb = (float)w[1];
}

__device__ __forceinline__ float qval(float A0, float A1, float A2, float A3) {
    float mul = A0 * A1;
    float sq  = fmaf(A0, A0, A1 * A1);
    float num = 4.f * fmaf(NN, A3, -mul) * mul;
    float dt  = fmaf(NN, A2, -sq);
    float den = dt * sq;
    bool  c1  = (dt == 0.f) && (sq != 0.f);
    float nn = num, dd = den;
    if (den == 0.f) { nn = c1 ? 2.f * mul : 1.f; dd = c1 ? sq : 1.f; }
    return nn * __builtin_amdgcn_rcpf(dd);
}

#define B31 (31 * CONV)

// quad q: 4 chains starting at rows 124q + {0,31,62,93}; quad 3 chain D has 16 rows
__global__ __launch_bounds__(256) void box_q5(
    const float* __restrict__ o,     // [NIMG][512][512]
    const float* __restrict__ lab,   // [NIMG][512][512]
    double* __restrict__ acc)        // acc[NIMG]
{
    int bid   = blockIdx.x;
    int img   = bid >> 4;
    int rr    = bid & 15;
    int rquad = rr >> 2;             // 0..3
    int xblk  = rr & 3;              // 0..3
    int lane  = threadIdx.x & 63;
    int wid   = threadIdx.x >> 6;    // 0..3

    int cb = xblk * 128 + wid * 32;
    int cc = min(cb + lane, CONV - 1);   // clamp: no per-iter masking
    int S0 = rquad * 124;

    const float* op = o   + (size_t)img * CONV * CONV + cc;
    const float* lp = lab + (size_t)img * CONV * CONV + cc;

    bool xvalid = (lane < 32) && (cb + lane < QOUT);

    float a0=0,a1=0,a2=0,a3=0;   // chain A (rows S0..)
    float b0=0,b1=0,b2=0,b3=0;   // chain B (S0+31)
    float c0=0,c1=0,c2=0,c3=0;   // chain C (S0+62)
    float d0=0,d1=0,d2=0,d3=0;   // chain D (S0+93)
    {
        int ofs = S0 * CONV;
#pragma unroll 2
        for (int k = 0; k < BS; ++k) {
            float oA = op[ofs],            lA = lp[ofs];
            float oB = op[ofs + B31],      lB = lp[ofs + B31];
            float oC = op[ofs + 2 * B31],  lC = lp[ofs + 2 * B31];
            float oD = op[ofs + 3 * B31],  lD = lp[ofs + 3 * B31];
            a0 += oA; a1 += lA; a2 = fmaf(oA, oA, fmaf(lA, lA, a2)); a3 = fmaf(oA, lA, a3);
            b0 += oB; b1 += lB; b2 = fmaf(oB, oB, fmaf(lB, lB, b2)); b3 = fmaf(oB, lB, b3);
            c0 += oC; c1 += lC; c2 = fmaf(oC, oC, fmaf(lC, lC, c2)); c3 = fmaf(oC, lC, c3);
            d0 += oD; d1 += lD; d2 = fmaf(oD, oD, fmaf(lD, lD, d2)); d3 = fmaf(oD, lD, d3);
            ofs += CONV;
        }
    }

    float qacc = 0.f;
    int iadd = (S0 + BS) * CONV;
    int isub = S0 * CONV;

    if (rquad < 3) {
        // uniform: all 4 chains, 31 outputs each, 30 slides
#pragma unroll 1
        for (int i = 0; i < 30; ++i) {
            float oAa = op[iadd],           lAa = lp[iadd];
            float oAs = op[isub],           lAs = lp[isub];
            float oBa = op[iadd + B31],     lBa = lp[iadd + B31];
            float oBs = op[isub + B31],     lBs = lp[isub + B31];
            float oCa = op[iadd + 2 * B31], lCa = lp[iadd + 2 * B31];
            float oCs = op[isub + 2 * B31], lCs = lp[isub + 2 * B31];
            float oDa = op[iadd + 3 * B31], lDa = lp[iadd + 3 * B31];
            float oDs = op[isub + 3 * B31], lDs = lp[isub + 3 * B31];

            float A0,A1,A2,A3, B0,B1,B2,B3, C0,C1,C2,C3, D0,D1,D2,D3;
            win32pair(a0, a1, lane, A0, A1); win32pair(a2, a3, lane, A2, A3);
            win32pair(b0, b1, lane, B0, B1); win32pair(b2, b3, lane, B2, B3);
            win32pair(c0, c1, lane, C0, C1); win32pair(c2, c3, lane, C2, C3);
            win32pair(d0, d1, lane, D0, D1); win32pair(d2, d3, lane, D2, D3);
            if (xvalid) {
                qacc += qval(A0, A1, A2, A3);
                qacc += qval(B0, B1, B2, B3);
                qacc += qval(C0, C1, C2, C3);
                qacc += qval(D0, D1, D2, D3);
            }

            a0 += oAa - oAs; a1 += lAa - lAs;
            a2 = fmaf(oAa, oAa, fmaf(lAa, lAa, fmaf(oAs, -oAs, fmaf(lAs, -lAs, a2))));
            a3 = fmaf(oAa, lAa, fmaf(oAs, -lAs, a3));
            b0 += oBa - oBs; b1 += lBa - lBs;
            b2 = fmaf(oBa, oBa, fmaf(lBa, lBa, fmaf(oBs, -oBs, fmaf(lBs, -lBs, b2))));
            b3 = fmaf(oBa, lBa, fmaf(oBs, -lBs, b3));
            c0 += oCa - oCs; c1 += lCa - lCs;
            c2 = fmaf(oCa, oCa, fmaf(lCa, lCa, fmaf(oCs, -oCs, fmaf(lCs, -lCs, c2))));
            c3 = fmaf(oCa, lCa, fmaf(oCs, -lCs, c3));
            d0 += oDa - oDs; d1 += lDa - lDs;
            d2 = fmaf(oDa, oDa, fmaf(lDa, lDa, fmaf(oDs, -oDs, fmaf(lDs, -lDs, d2))));
            d3 = fmaf(oDa, lDa, fmaf(oDs, -lDs, d3));
            iadd += CONV; isub += CONV;
        }
        {   // i = 30: outputs only
            float A0,A1,A2,A3, B0,B1,B2,B3, C0,C1,C2,C3, D0,D1,D2,D3;
            win32pair(a0, a1, lane, A0, A1); win32pair(a2, a3, lane, A2, A3);
            win32pair(b0, b1, lane, B0, B1); win32pair(b2, b3, lane, B2, B3);
            win32pair(c0, c1, lane, C0, C1); win32pair(c2, c3, lane, C2, C3);
            win32pair(d0, d1, lane, D0, D1); win32pair(d2, d3, lane, D2, D3);
            if (xvalid) {
                qacc += qval(A0, A1, A2, A3);
                qacc += qval(B0, B1, B2, B3);
                qacc += qval(C0, C1, C2, C3);
                qacc += qval(D0, D1, D2, D3);
            }
        }
    } else {
        // quad 3: chains A,B,C full 31 outputs; chain D 16 outputs (rows 465..480)
#pragma unroll 1
        for (int i = 0; i < 31; ++i) {
            bool mABC = (i < 30), mD = (i + 1 < 16);
            float oAa=0,lAa=0,oAs=0,lAs=0, oBa=0,lBa=0,oBs=0,lBs=0;
            float oCa=0,lCa=0,oCs=0,lCs=0, oDa=0,lDa=0,oDs=0,lDs=0;
            if (mABC) {
                oAa = op[iadd];           lAa = lp[iadd];
                oAs = op[isub];           lAs = lp[isub];
                oBa = op[iadd + B31];     lBa = lp[iadd + B31];
                oBs = op[isub + B31];     lBs = lp[isub + B31];
                oCa = op[iadd + 2 * B31]; lCa = lp[iadd + 2 * B31];
                oCs = op[isub + 2 * B31]; lCs = lp[isub + 2 * B31];
            }
            if (mD) {
                oDa = op[iadd + 3 * B31]; lDa = lp[iadd + 3 * B31];
                oDs = op[isub + 3 * B31]; lDs = lp[isub + 3 * B31];
            }

            {
                float A0,A1,A2,A3, B0,B1,B2,B3, C0,C1,C2,C3;
                win32pair(a0, a1, lane, A0, A1); win32pair(a2, a3, lane, A2, A3);
                win32pair(b0, b1, lane, B0, B1); win32pair(b2, b3, lane, B2, B3);
                win32pair(c0, c1, lane, C0, C1); win32pair(c2, c3, lane, C2, C3);
                if (xvalid) {
                    qacc += qval(A0, A1, A2, A3);
                    qacc += qval(B0, B1, B2, B3);
                    qacc += qval(C0, C1, C2, C3);
                }
            }
            if (i < 16) {
                float D0,D1,D2,D3;
                win32pair(d0, d1, lane, D0, D1); win32pair(d2, d3, lane, D2, D3);
                if (xvalid) qacc += qval(D0, D1, D2, D3);
            }

            a0 += oAa - oAs; a1 += lAa - lAs;
            a2 = fmaf(oAa, oAa, fmaf(lAa, lAa, fmaf(oAs, -oAs, fmaf(lAs, -lAs, a2))));
            a3 = fmaf(oAa, lAa, fmaf(oAs, -lAs, a3));
            b0 += oBa - oBs; b1 += lBa - lBs;
            b2 = fmaf(oBa, oBa, fmaf(lBa, lBa, fmaf(oBs, -oBs, fmaf(lBs, -lBs, b2))));
            b3 = fmaf(oBa, lBa, fmaf(oBs, -lBs, b3));
            c0 += oCa - oCs; c1 += lCa - lCs;
            c2 = fmaf(oCa, oCa, fmaf(lCa, lCa, fmaf(oCs, -oCs, fmaf(lCs, -lCs, c2))));
            c3 = fmaf(oCa, lCa, fmaf(oCs, -lCs, c3));
            d0 += oDa - oDs; d1 += lDa - lDs;
            d2 = fmaf(oDa, oDa, fmaf(lDa, lDa, fmaf(oDs, -oDs, fmaf(lDs, -lDs, d2))));
            d3 = fmaf(oDa, lDa, fmaf(oDs, -lDs, d3));
            iadd += CONV; isub += CONV;
        }
    }

    qacc += __shfl_down(qacc, 16, 64);
    qacc += __shfl_down(qacc, 8, 64);
    qacc += __shfl_down(qacc, 4, 64);
    qacc += __shfl_down(qacc, 2, 64);
    qacc += __shfl_down(qacc, 1, 64);
    if (lane == 0) atomicAdd(&acc[img], (double)qacc);
}

__global__ void finalize_kernel(const double* __restrict__ acc, float* __restrict__ out)
{
    double t = 0.0;
    for (int i = 0; i < NIMG; ++i) t += acc[i];
    out[0] = 1.0f - (float)(t / 7403552.0);   // 4*8*481*481
}

extern "C" void kernel_launch(void* const* d_in, const int* in_sizes, int n_in,
                              void* d_out, int out_size, void* d_ws, size_t ws_size,
                              hipStream_t stream)
{
    const float* outputs = (const float*)d_in[0];   // [4,8,552,552]
    const float* labels  = (const float*)d_in[1];   // [4,8,512,512]
    const float* mtf     = (const float*)d_in[2];   // [8,1,41,41]

    double*    acc   = (double*)d_ws;                                   // @0
    float*     o_buf = (float*)((char*)d_ws + 4096);                    // 33.55 MB
    _Float16*  T     = (_Float16*)((char*)d_ws + 4096 + 33554432);      // 20.64 MB
    _Float16*  Atab  = (_Float16*)((char*)d_ws + 4096 + 33554432 + 20643840); // 2.15 MB

    // allow >64KB dynamic LDS (idempotent)
    (void)hipFuncSetAttribute((const void*)conv_mfma_512,
                              hipFuncAttributeMaxDynamicSharedMemorySize,
                              22 * XP4 * 16);

    hipMemsetAsync(d_ws, 0, 256, stream);

    prep_transpose<<<NIMG * 81, 256, 0, stream>>>(outputs, T);
    prep_atab32<<<NBANDS * KXP, 320, 0, stream>>>(mtf, Atab);
    conv_mfma_512<<<NIMG * 8, 512, 22 * XP4 * 16, stream>>>(T, Atab, o_buf);
    box_q5<<<NIMG * 16, 256, 0, stream>>>(o_buf, labels, acc);
    finalize_kernel<<<1, 1, 0, stream>>>(acc, (float*)d_out);
}

// Round 15
// 120.420 us; speedup vs baseline: 1.1044x; 1.1044x over previous
//
#include <hip/hip_runtime.h>

// Problem constants
#define NBANDS 8
#define BS 32
#define MTF 41
#define IMG 552
#define CONV 512
#define QOUT 481
#define NIMG 32
#define NN 1024.0f
#define KXP 42            // Atab kx entries per band (41 real + 1 zero pad)

// Transposed fp16 input T: [NIMG][TX][TY], zero-padded
#define TX 560
#define TY 576

typedef _Float16 half8 __attribute__((ext_vector_type(8)));
typedef _Float16 half2v __attribute__((ext_vector_type(2)));
typedef float f32x4 __attribute__((ext_vector_type(4)));

// ---------- prep 1: transpose + fp16 convert ----------
__global__ __launch_bounds__(256) void prep_transpose(
    const float* __restrict__ in, _Float16* __restrict__ T)
{
    __shared__ _Float16 s[64][72];
    int bid = blockIdx.x;
    int img = bid / 81;            // 9x9 tiles of 64
    int t = bid % 81;
    int ty = t / 9, tx2 = t % 9;
    int y0 = ty * 64, x0 = tx2 * 64;
    const float* ip = in + (size_t)img * IMG * IMG;

    for (int k = 0; k < 16; ++k) {
        int i = k * 256 + threadIdx.x;
        int r = i >> 6, c = i & 63;
        int y = y0 + r, x = x0 + c;
        float v = (y < IMG && x < IMG) ? ip[(size_t)y * IMG + x] : 0.f;
        s[c][r] = (_Float16)v;
    }
    __syncthreads();
    _Float16* Tp = T + (size_t)img * TX * TY;
    for (int k = 0; k < 2; ++k) {
        int i = k * 256 + threadIdx.x;  // 512 = 64 xi * 8 g
        int xi = i >> 3, g = i & 7;
        int x = x0 + xi;
        if (x < TX) {
            half8 v = *(const half8*)&s[xi][g * 8];
            *(half8*)&Tp[(size_t)x * TY + y0 + g * 8] = v;
        }
    }
}

// ---------- prep 2: Toeplitz A-table for 16x16x32 MFMA (K=64: 2 slabs; 42 kx) ----------
// A[i][kabs] = w[kabs - i][kx], i = out-row (0..15), kabs = 32s + (lane>>4)*8 + j
__global__ __launch_bounds__(128) void prep_atab16(
    const float* __restrict__ w, _Float16* __restrict__ A)
{
    int bid = blockIdx.x;                 // band*KXP + kx
    int band = bid / KXP, kx = bid % KXP;
    int s = threadIdx.x >> 6, lane = threadIdx.x & 63;
    int i = lane & 15;
    int kb = 32 * s + ((lane >> 4) << 3);
    const float* wp = w + band * MTF * MTF;
    half8 v;
#pragma unroll
    for (int j = 0; j < 8; ++j) {
        int ky = kb + j - i;
        v[j] = (kx < MTF && ky >= 0 && ky < MTF) ? (_Float16)wp[ky * MTF + kx]
                                                 : (_Float16)0.f;
    }
    *(half8*)&A[(((size_t)(bid * 2 + s)) << 9) + lane * 8] = v;
}

// ---------- Kernel A: 16x16x32 MFMA conv, wave = 128y x 16x, frag-sharing ----------
// Block: 4 waves side-by-side in x -> 128y x 64x outputs. Grid 1024 -> 4 blocks/CU.
// LDS: 22 8-row y-groups x 105-pitch x-cols = 36960 B -> 16 waves/CU.
// Per wave per kx: 10 distinct b128 fragments (u=0,2,..,18) serve 16 MFMAs.
#define XP5 105
#define UGS (2 * XP5 * 16)    // byte stride between u-steps (u increments of 2): 3360

__global__ __launch_bounds__(256, 4) void conv_mfma16(
    const _Float16* __restrict__ T, const _Float16* __restrict__ Atab,
    float* __restrict__ out)
{
    __shared__ __align__(16) _Float16 sB[22 * XP5 * 8];   // 36960 B
    int bid = blockIdx.x;
    int img = bid >> 5;
    int rr  = bid & 31;
    int y0 = (rr >> 3) << 7;       // 0..384
    int x0 = (rr & 7) << 6;        // 0..448
    int band = img & 7;
    int tid = threadIdx.x;

    const _Float16* Tp = T + (size_t)img * TX * TY;
    for (int e = tid; e < 22 * 104; e += 256) {
        int g = e / 104, x = e - g * 104;
        half8 v = *(const half8*)&Tp[(size_t)(x0 + x) * TY + y0 + g * 8];
        *(half8*)&sB[(size_t)(g * XP5 + x) * 8] = v;
    }
    __syncthreads();

    int l  = tid & 63;
    int wx = tid >> 6;             // 0..3 (16-col x sub-tile)
    int g4 = l >> 4;               // k-quarter -> y-group offset
    int ln = l & 15;

    const half8* Ab = (const half8*)Atab + (size_t)band * KXP * 2 * 64 + l;
    const char* bbase = (const char*)sB + ((size_t)(g4 * XP5 + (wx << 4) + ln) << 4);

    f32x4 acc[8] = {};             // 8 independent MFMA chains (one per 16-row y-tile)

    auto LDA = [&](half8 (&A)[2], int kx) {
        A[0] = Ab[(size_t)(kx * 2) * 64];
        A[1] = Ab[(size_t)(kx * 2 + 1) * 64];
    };
    auto LDB = [&](half8 (&B)[10], int kx) {
        const char* q = bbase + ((size_t)kx << 4);
#pragma unroll
        for (int i = 0; i < 10; ++i) B[i] = *(const half8*)(q + i * UGS);
    };
    auto FMAS = [&](half8 (&A)[2], half8 (&B)[10]) {
        // slab 0: u = 2t ; slab 1: u = 2t+4 -> B[t+2]
#pragma unroll
        for (int t = 0; t < 8; ++t)
            acc[t] = __builtin_amdgcn_mfma_f32_16x16x32_f16(A[0], B[t], acc[t], 0, 0, 0);
#pragma unroll
        for (int t = 0; t < 8; ++t)
            acc[t] = __builtin_amdgcn_mfma_f32_16x16x32_f16(A[1], B[t + 2], acc[t], 0, 0, 0);
    };

    half8 A0[2], A1[2], B[10];
    LDA(A0, 0);
#pragma unroll 1
    for (int kx = 0; kx < 40; kx += 2) {
        LDB(B, kx);
        LDA(A1, kx + 1);
        FMAS(A0, B);
        LDB(B, kx + 1);
        LDA(A0, kx + 2);           // <= 41 (zero-padded entry)
        FMAS(A1, B);
    }
    LDB(B, 40);
    FMAS(A0, B);

    // C/D layout (16x16): col = l&15, row = (l>>4)*4 + r
    float* op = out + (size_t)img * CONV * CONV;
    int col = x0 + (wx << 4) + ln;
    int rb  = y0 + (g4 << 2);
#pragma unroll
    for (int t = 0; t < 8; ++t) {
#pragma unroll
        for (int r = 0; r < 4; ++r)
            op[(size_t)(rb + 16 * t + r) * CONV + col] = acc[t][r];
    }
}

// ---------------- Kernel B: box-sums + Q with packed-f16 scans (R13 best) ----------------
template<int C, int RM, int BM, bool BC>
__device__ __forceinline__ int dppadd_h2(int v) {
    int t = __builtin_amdgcn_update_dpp(0, v, C, RM, BM, BC);
    half2v a = __builtin_bit_cast(half2v, v);
    half2v b = __builtin_bit_cast(half2v, t);
    return __builtin_bit_cast(int, a + b);
}

__device__ __forceinline__ int wave_iscan_h2(int v) {
    v = dppadd_h2<0x111, 0xf, 0xf, true >(v);   // row_shr:1
    v = dppadd_h2<0x112, 0xf, 0xf, true >(v);   // row_shr:2
    v = dppadd_h2<0x114, 0xf, 0xf, true >(v);   // row_shr:4
    v = dppadd_h2<0x118, 0xf, 0xf, true >(v);   // row_shr:8
    v = dppadd_h2<0x142, 0xa, 0xf, false>(v);   // row_bcast:15 -> rows 1,3
    v = dppadd_h2<0x143, 0xc, 0xf, false>(v);   // row_bcast:31 -> rows 2,3
    return v;
}

__device__ __forceinline__ void win32pair(float sa, float sb, int lane,
                                          float& wa, float& wb) {
    half2v p = __builtin_bit_cast(half2v, __builtin_amdgcn_cvt_pkrtz(sa, sb));
    int P = wave_iscan_h2(__builtin_bit_cast(int, p));
    int Pg = __shfl(P, lane + 31, 64);
    half2v w = __builtin_bit_cast(half2v, Pg) - __builtin_bit_cast(half2v, P) + p;
    wa = (float)w[0];
    wb = (float)w[1];
}

__device__ __forceinline__ float qval(float A0, float A1, float A2, float A3) {
    float mul = A0 * A1;
    float sq  = fmaf(A0, A0, A1 * A1);
    float num = 4.f * fmaf(NN, A3, -mul) * mul;
    float dt  = fmaf(NN, A2, -sq);
    float den = dt * sq;
    bool  c1  = (dt == 0.f) && (sq != 0.f);
    float nn = num, dd = den;
    if (den == 0.f) { nn = c1 ? 2.f * mul : 1.f; dd = c1 ? sq : 1.f; }
    return nn * __builtin_amdgcn_rcpf(dd);
}

#define B_OFF (31 * CONV)

__global__ __launch_bounds__(512) void box_q4(
    const float* __restrict__ o,     // [NIMG][512][512]
    const float* __restrict__ lab,   // [NIMG][512][512]
    double* __restrict__ acc)        // acc[NIMG]
{
    int bid  = blockIdx.x;
    int img  = bid >> 4;
    int rr   = bid & 15;
    int pair = rr >> 1;
    int xblk = rr & 1;
    int lane = threadIdx.x & 63;
    int wid  = threadIdx.x >> 6;

    int c0 = xblk * 256 + wid * 32;
    int cc = min(c0 + lane, CONV - 1);   // clamp: no per-iter masking needed
    int r0A = pair * 62;

    const float* op = o   + (size_t)img * CONV * CONV + cc;
    const float* lp = lab + (size_t)img * CONV * CONV + cc;

    bool xvalid = (lane < 32) && (c0 + lane < QOUT);

    float sA0=0,sA1=0,sA2=0,sA3=0, sB0=0,sB1=0,sB2=0,sB3=0;
    {
        int ofs = r0A * CONV;
#pragma unroll 4
        for (int k = 0; k < BS; ++k) {
            float ov = op[ofs],         lv = lp[ofs];
            float ow = op[ofs + B_OFF], lw = lp[ofs + B_OFF];
            sA0 += ov; sA1 += lv;
            sA2 = fmaf(ov, ov, fmaf(lv, lv, sA2)); sA3 = fmaf(ov, lv, sA3);
            sB0 += ow; sB1 += lw;
            sB2 = fmaf(ow, ow, fmaf(lw, lw, sB2)); sB3 = fmaf(ow, lw, sB3);
            ofs += CONV;
        }
    }

    float qacc = 0.f;
    int iadd = (r0A + BS) * CONV;
    int isub = r0A * CONV;

    if (pair < 7) {
#pragma unroll 1
        for (int i = 0; i < 30; ++i) {
            float oa = op[iadd],         la2 = lp[iadd];
            float ob = op[isub],         lb  = lp[isub];
            float oc = op[iadd + B_OFF], lc  = lp[iadd + B_OFF];
            float od = op[isub + B_OFF], ld  = lp[isub + B_OFF];

            float A0, A1, A2, A3, B0, B1, B2, B3;
            win32pair(sA0, sA1, lane, A0, A1);
            win32pair(sA2, sA3, lane, A2, A3);
            win32pair(sB0, sB1, lane, B0, B1);
            win32pair(sB2, sB3, lane, B2, B3);
            if (xvalid) {
                qacc += qval(A0, A1, A2, A3);
                qacc += qval(B0, B1, B2, B3);
            }

            sA0 += oa - ob; sA1 += la2 - lb;
            sA2 = fmaf(oa, oa, fmaf(la2, la2, fmaf(ob, -ob, fmaf(lb, -lb, sA2))));
            sA3 = fmaf(oa, la2, fmaf(ob, -lb, sA3));
            sB0 += oc - od; sB1 += lc - ld;
            sB2 = fmaf(oc, oc, fmaf(lc, lc, fmaf(od, -od, fmaf(ld, -ld, sB2))));
            sB3 = fmaf(oc, lc, fmaf(od, -ld, sB3));
            iadd += CONV; isub += CONV;
        }
        {   // final outputs (i = 30), no slide
            float A0, A1, A2, A3, B0, B1, B2, B3;
            win32pair(sA0, sA1, lane, A0, A1);
            win32pair(sA2, sA3, lane, A2, A3);
            win32pair(sB0, sB1, lane, B0, B1);
            win32pair(sB2, sB3, lane, B2, B3);
            if (xvalid) {
                qacc += qval(A0, A1, A2, A3);
                qacc += qval(B0, B1, B2, B3);
            }
        }
    } else {
        // pair 7: chain A 31 outputs, chain B 16 outputs (rows 465..480)
#pragma unroll 1
        for (int i = 0; i < 31; ++i) {
            bool mA = (i < 30), mB = (i + 1 < 16);
            float oa=0,la2=0,ob=0,lb=0, oc=0,lc=0,od=0,ld=0;
            if (mA) {
                oa = op[iadd]; la2 = lp[iadd];
                ob = op[isub]; lb  = lp[isub];
            }
            if (mB) {
                oc = op[iadd + B_OFF]; lc = lp[iadd + B_OFF];
                od = op[isub + B_OFF]; ld = lp[isub + B_OFF];
            }

            {
                float A0, A1, A2, A3;
                win32pair(sA0, sA1, lane, A0, A1);
                win32pair(sA2, sA3, lane, A2, A3);
                if (xvalid) qacc += qval(A0, A1, A2, A3);
            }
            if (i < 16) {
                float B0, B1, B2, B3;
                win32pair(sB0, sB1, lane, B0, B1);
                win32pair(sB2, sB3, lane, B2, B3);
                if (xvalid) qacc += qval(B0, B1, B2, B3);
            }

            sA0 += oa - ob; sA1 += la2 - lb;
            sA2 = fmaf(oa, oa, fmaf(la2, la2, fmaf(ob, -ob, fmaf(lb, -lb, sA2))));
            sA3 = fmaf(oa, la2, fmaf(ob, -lb, sA3));
            sB0 += oc - od; sB1 += lc - ld;
            sB2 = fmaf(oc, oc, fmaf(lc, lc, fmaf(od, -od, fmaf(ld, -ld, sB2))));
            sB3 = fmaf(oc, lc, fmaf(od, -ld, sB3));
            iadd += CONV; isub += CONV;
        }
    }

    qacc += __shfl_down(qacc, 16, 64);
    qacc += __shfl_down(qacc, 8, 64);
    qacc += __shfl_down(qacc, 4, 64);
    qacc += __shfl_down(qacc, 2, 64);
    qacc += __shfl_down(qacc, 1, 64);
    if (lane == 0) atomicAdd(&acc[img], (double)qacc);
}

__global__ void finalize_kernel(const double* __restrict__ acc, float* __restrict__ out)
{
    double t = 0.0;
    for (int i = 0; i < NIMG; ++i) t += acc[i];
    out[0] = 1.0f - (float)(t / 7403552.0);   // 4*8*481*481
}

extern "C" void kernel_launch(void* const* d_in, const int* in_sizes, int n_in,
                              void* d_out, int out_size, void* d_ws, size_t ws_size,
                              hipStream_t stream)
{
    const float* outputs = (const float*)d_in[0];   // [4,8,552,552]
    const float* labels  = (const float*)d_in[1];   // [4,8,512,512]
    const float* mtf     = (const float*)d_in[2];   // [8,1,41,41]

    double*    acc   = (double*)d_ws;                                   // @0
    float*     o_buf = (float*)((char*)d_ws + 4096);                    // 33.55 MB
    _Float16*  T     = (_Float16*)((char*)d_ws + 4096 + 33554432);      // 20.64 MB
    _Float16*  Atab  = (_Float16*)((char*)d_ws + 4096 + 33554432 + 20643840); // 688 KB

    hipMemsetAsync(d_ws, 0, 256, stream);

    prep_transpose<<<NIMG * 81, 256, 0, stream>>>(outputs, T);
    prep_atab16<<<NBANDS * KXP, 128, 0, stream>>>(mtf, Atab);
    conv_mfma16<<<NIMG * 32, 256, 0, stream>>>(T, Atab, o_buf);
    box_q4<<<NIMG * 16, 512, 0, stream>>>(o_buf, labels, acc);
    finalize_kernel<<<1, 1, 0, stream>>>(acc, (float*)d_out);
}